// Round 8
// baseline (123.307 us; speedup 1.0000x reference)
//
#include <hip/hip_runtime.h>

// Problem constants
#define BB 2
#define SS 1024
#define DD 768
#define HH 128
#define LL 51

typedef float f32x4 __attribute__((ext_vector_type(4)));

// Workspace layout (floats):
//  wt  : [192][128][4] @ 0       fused weights, transposed-packed:
//                                wt[d4][l][k]      = (Wv·Wu)[l][d4*4+k]
//                                wt[d4][51+l][k]   = (Wv·Ww)[l][d4*4+k]
//  cP  : [51]          @ 98304   (Wv·(bu+bias) + bv)
//  cQ  : [51]          @ 98368   (Wv·bw)
//  P   : [2048][51]    @ 98432   (g-order: P[row*51+l] = row-l value)
//  Qt  : [2][51][1024] @ 202880
#define OFF_WT 0
#define OFF_CP 98304
#define OFF_CQ 98368
#define OFF_P  98432
#define OFF_QT 202880

// Kernel 1: fold Wv into Wu/Ww (and biases into per-l constants), writing the
// transposed-packed wt layout so proj's weight reads are lane-coalesced.
// Grid 204 = 51 l × 4 d-chunks of 192 columns; 256 threads.
__global__ __launch_bounds__(256) void fuse_weights(
    const float* __restrict__ Wu, const float* __restrict__ bu,
    const float* __restrict__ Ww, const float* __restrict__ bw,
    const float* __restrict__ Wv, const float* __restrict__ bv,
    const float* __restrict__ bias, float* __restrict__ ws) {
  __shared__ float wv[HH];
  const int l  = blockIdx.x >> 2;
  const int ch = blockIdx.x & 3;
  const int t  = threadIdx.x;
  if (t < HH) wv[t] = Wv[l * HH + t];
  __syncthreads();

  if (t < 192) {
    const int d = ch * 192 + t;
    float au = 0.f, aw = 0.f;
#pragma unroll 8
    for (int h = 0; h < HH; ++h) {
      au += wv[h] * Wu[h * DD + d];   // lanes: consecutive d -> coalesced
      aw += wv[h] * Ww[h * DD + d];
    }
    float* wt = ws + OFF_WT;
    wt[((d >> 2) * 128 + l) * 4 + (d & 3)]        = au;
    wt[((d >> 2) * 128 + (LL + l)) * 4 + (d & 3)] = aw;
  }
  if (ch == 0 && t == 0) {
    float a = 0.f, cc = 0.f;
#pragma unroll 8
    for (int h = 0; h < HH; ++h) {
      a  += wv[h] * (bu[h] + bias[h]);
      cc += wv[h] * bw[h];
    }
    ws[OFF_CP + l] = a + bv[l];
    ws[OFF_CQ + l] = cc;
  }
}

// Kernel 2: P[row][l] = x[row]·WuV[l] + cP[l];  Qt[b][l][j] = x[row]·WwV[l] + cQ[l]
// TM=4 rows per block -> 512 blocks (2 blocks/CU, 8 waves/CU), 256 threads.
// Thread (c = t&127, rg = t>>7): column c over 2 rows.
#define TM 4
__global__ __launch_bounds__(256) void proj(
    const float* __restrict__ x, float* __restrict__ ws) {
  __shared__ float xs[TM * DD];  // 12 KiB
  const int t = threadIdx.x;
  const long base = (long)blockIdx.x * TM * DD;

  const f32x4* x4 = (const f32x4*)(x + base);
  f32x4* xs4 = (f32x4*)xs;
#pragma unroll
  for (int k = 0; k < (TM * DD / 4) / 256; ++k)  // 3 iters
    xs4[t + k * 256] = x4[t + k * 256];
  __syncthreads();

  const int c = t & 127;
  const int rg = t >> 7;
  if (c >= 2 * LL) return;

  const float* wt = ws + OFF_WT;
  const float* xrow = xs + (rg * 2) * DD;

  float acc[2] = {0.f, 0.f};
#pragma unroll 4
  for (int d4 = 0; d4 < DD / 4; ++d4) {
    f32x4 w = *(const f32x4*)(wt + (d4 * 128 + c) * 4);  // lane-coalesced L2
#pragma unroll
    for (int r = 0; r < 2; ++r) {
      f32x4 xv = *(const f32x4*)(xrow + r * DD + d4 * 4);  // wave-uniform
      acc[r] += w.x * xv.x + w.y * xv.y + w.z * xv.z + w.w * xv.w;
    }
  }

  const int row0 = blockIdx.x * TM + rg * 2;
  if (c < LL) {
    const float add = ws[OFF_CP + c];
#pragma unroll
    for (int r = 0; r < 2; ++r) ws[OFF_P + (row0 + r) * LL + c] = acc[r] + add;
  } else {
    const int l = c - LL;
    const float add = ws[OFF_CQ + l];
#pragma unroll
    for (int r = 0; r < 2; ++r) {
      const int row = row0 + r;
      const int b = row >> 10, j = row & (SS - 1);
      ws[OFF_QT + ((long)(b * LL + l)) * SS + j] = acc[r] + add;
    }
  }
}

// Kernel 3: out[b,i,l,j] = P[b*S+i][l] + Qt[b][l][j].
// Grid-stride sweep (round 7) but with PLAIN write-back stores instead of NT:
// this is the exact fillBuffer configuration (compact sweeping front + L2
// write-combining), the one untested cell of the {NT,plain}x{regions,sweep}
// matrix. Risk: write stream churns L2 and evicts Qt (~418 KB) -> bounded
// ~+6 us of refetch; upside: NT bypass path was the 4.5 TB/s limiter.
#define GEXP 2048
__global__ __launch_bounds__(256) void expand(
    const float* __restrict__ ws, float* __restrict__ out) {
  const int t = threadIdx.x;
  const int NCH = BB * SS * LL;  // 104448 chunks of 4 KB
  for (int g = blockIdx.x; g < NCH; g += GEXP) {  // 51 iters, no remainder
    const int row = g / LL;      // b*S + i  (magic-mul)
    const int l   = g - row * LL;
    const int b   = row >> 10;
    const float p = ws[OFF_P + g];  // block-uniform -> scalar load
    const f32x4 q = *((const f32x4*)(ws + OFF_QT + ((long)(b * LL + l)) * SS) + t);
    f32x4 v = q + p;
    *((f32x4*)(out + (long)g * SS) + t) = v;  // plain store (write-back L2)
  }
}

extern "C" void kernel_launch(void* const* d_in, const int* in_sizes, int n_in,
                              void* d_out, int out_size, void* d_ws, size_t ws_size,
                              hipStream_t stream) {
  const float* x    = (const float*)d_in[0];
  const float* Wu   = (const float*)d_in[1];
  const float* bu   = (const float*)d_in[2];
  const float* Ww   = (const float*)d_in[3];
  const float* bw   = (const float*)d_in[4];
  const float* Wv   = (const float*)d_in[5];
  const float* bv   = (const float*)d_in[6];
  const float* bias = (const float*)d_in[7];
  float* out = (float*)d_out;
  float* ws  = (float*)d_ws;

  fuse_weights<<<dim3(LL * 4), dim3(256), 0, stream>>>(Wu, bu, Ww, bw, Wv, bv, bias, ws);
  proj<<<dim3((BB * SS) / TM), dim3(256), 0, stream>>>(x, ws);
  expand<<<dim3(GEXP), dim3(256), 0, stream>>>(ws, out);
}

// Round 9
// 110.897 us; speedup vs baseline: 1.1119x; 1.1119x over previous
//
#include <hip/hip_runtime.h>

// Problem constants
#define BB 2
#define SS 1024
#define DD 768
#define HH 128
#define LL 51

typedef float f32x4 __attribute__((ext_vector_type(4)));

// Workspace layout (floats):
//  wt  : [192][128][4] @ 0       fused weights, transposed-packed:
//                                wt[d4][l][k]      = (Wv·Wu)[l][d4*4+k]
//                                wt[d4][51+l][k]   = (Wv·Ww)[l][d4*4+k]
//  cP  : [51]          @ 98304   (Wv·(bu+bias) + bv)
//  cQ  : [51]          @ 98368   (Wv·bw)
//  P   : [2048][51]    @ 98432   (g-order: P[row*51+l] = row-l value)
//  Qt  : [2][51][1024] @ 202880
#define OFF_WT 0
#define OFF_CP 98304
#define OFF_CQ 98368
#define OFF_P  98432
#define OFF_QT 202880

// Kernel 1: fold Wv into Wu/Ww (and biases into per-l constants), writing the
// transposed-packed wt layout so proj's weight reads are lane-coalesced.
// Grid 204 = 51 l × 4 d-chunks of 192 columns; 256 threads.
__global__ __launch_bounds__(256) void fuse_weights(
    const float* __restrict__ Wu, const float* __restrict__ bu,
    const float* __restrict__ Ww, const float* __restrict__ bw,
    const float* __restrict__ Wv, const float* __restrict__ bv,
    const float* __restrict__ bias, float* __restrict__ ws) {
  __shared__ float wv[HH];
  const int l  = blockIdx.x >> 2;
  const int ch = blockIdx.x & 3;
  const int t  = threadIdx.x;
  if (t < HH) wv[t] = Wv[l * HH + t];
  __syncthreads();

  if (t < 192) {
    const int d = ch * 192 + t;
    float au = 0.f, aw = 0.f;
#pragma unroll 8
    for (int h = 0; h < HH; ++h) {
      au += wv[h] * Wu[h * DD + d];   // lanes: consecutive d -> coalesced
      aw += wv[h] * Ww[h * DD + d];
    }
    float* wt = ws + OFF_WT;
    wt[((d >> 2) * 128 + l) * 4 + (d & 3)]        = au;
    wt[((d >> 2) * 128 + (LL + l)) * 4 + (d & 3)] = aw;
  }
  if (ch == 0 && t == 0) {
    float a = 0.f, cc = 0.f;
#pragma unroll 8
    for (int h = 0; h < HH; ++h) {
      a  += wv[h] * (bu[h] + bias[h]);
      cc += wv[h] * bw[h];
    }
    ws[OFF_CP + l] = a + bv[l];
    ws[OFF_CQ + l] = cc;
  }
}

// Kernel 2: P[row][l] = x[row]·WuV[l] + cP[l];  Qt[b][l][j] = x[row]·WwV[l] + cQ[l]
// TM=4 rows per block -> 512 blocks (2 blocks/CU, 8 waves/CU), 256 threads.
// Thread (c = t&127, rg = t>>7): column c over 2 rows.
#define TM 4
__global__ __launch_bounds__(256) void proj(
    const float* __restrict__ x, float* __restrict__ ws) {
  __shared__ float xs[TM * DD];  // 12 KiB
  const int t = threadIdx.x;
  const long base = (long)blockIdx.x * TM * DD;

  const f32x4* x4 = (const f32x4*)(x + base);
  f32x4* xs4 = (f32x4*)xs;
#pragma unroll
  for (int k = 0; k < (TM * DD / 4) / 256; ++k)  // 3 iters
    xs4[t + k * 256] = x4[t + k * 256];
  __syncthreads();

  const int c = t & 127;
  const int rg = t >> 7;
  if (c >= 2 * LL) return;

  const float* wt = ws + OFF_WT;
  const float* xrow = xs + (rg * 2) * DD;

  float acc[2] = {0.f, 0.f};
#pragma unroll 4
  for (int d4 = 0; d4 < DD / 4; ++d4) {
    f32x4 w = *(const f32x4*)(wt + (d4 * 128 + c) * 4);  // lane-coalesced L2
#pragma unroll
    for (int r = 0; r < 2; ++r) {
      f32x4 xv = *(const f32x4*)(xrow + r * DD + d4 * 4);  // wave-uniform
      acc[r] += w.x * xv.x + w.y * xv.y + w.z * xv.z + w.w * xv.w;
    }
  }

  const int row0 = blockIdx.x * TM + rg * 2;
  if (c < LL) {
    const float add = ws[OFF_CP + c];
#pragma unroll
    for (int r = 0; r < 2; ++r) ws[OFF_P + (row0 + r) * LL + c] = acc[r] + add;
  } else {
    const int l = c - LL;
    const float add = ws[OFF_CQ + l];
#pragma unroll
    for (int r = 0; r < 2; ++r) {
      const int row = row0 + r;
      const int b = row >> 10, j = row & (SS - 1);
      ws[OFF_QT + ((long)(b * LL + l)) * SS + j] = acc[r] + add;
    }
  }
}

// Kernel 3: out[b,i,l,j] = P[b*S+i][l] + Qt[b][l][j].
// Best-measured configuration (round 7, 114.0 us): fillBuffer-shaped
// grid-stride sweep + NT stores. Full A/B matrix over
// {NT,plain} x {block-regions, sweep} x {L2, LDS reads} showed: NT > plain
// by ~8 us everywhere; read placement neutral; sweep best. Restored verbatim.
#define GEXP 2048
__global__ __launch_bounds__(256) void expand(
    const float* __restrict__ ws, float* __restrict__ out) {
  const int t = threadIdx.x;
  const int NCH = BB * SS * LL;  // 104448 chunks of 4 KB
  for (int g = blockIdx.x; g < NCH; g += GEXP) {  // 51 iters, no remainder
    const int row = g / LL;      // b*S + i  (magic-mul)
    const int l   = g - row * LL;
    const int b   = row >> 10;
    const float p = ws[OFF_P + g];  // block-uniform -> scalar load
    const f32x4 q = *((const f32x4*)(ws + OFF_QT + ((long)(b * LL + l)) * SS) + t);
    f32x4 v = q + p;
    __builtin_nontemporal_store(v, (f32x4*)(out + (long)g * SS) + t);
  }
}

extern "C" void kernel_launch(void* const* d_in, const int* in_sizes, int n_in,
                              void* d_out, int out_size, void* d_ws, size_t ws_size,
                              hipStream_t stream) {
  const float* x    = (const float*)d_in[0];
  const float* Wu   = (const float*)d_in[1];
  const float* bu   = (const float*)d_in[2];
  const float* Ww   = (const float*)d_in[3];
  const float* bw   = (const float*)d_in[4];
  const float* Wv   = (const float*)d_in[5];
  const float* bv   = (const float*)d_in[6];
  const float* bias = (const float*)d_in[7];
  float* out = (float*)d_out;
  float* ws  = (float*)d_ws;

  fuse_weights<<<dim3(LL * 4), dim3(256), 0, stream>>>(Wu, bu, Ww, bw, Wv, bv, bias, ws);
  proj<<<dim3((BB * SS) / TM), dim3(256), 0, stream>>>(x, ws);
  expand<<<dim3(GEXP), dim3(256), 0, stream>>>(ws, out);
}